// Round 8
// baseline (262.184 us; speedup 1.0000x reference)
//
#include <hip/hip_runtime.h>
#include <hip/hip_bf16.h>
#include <hip/hip_cooperative_groups.h>

namespace cg = cooperative_groups;

#define S 1024
#define C 384
#define NC 32
#define SHIFT 0.3f

typedef __attribute__((ext_vector_type(4))) float f32x4;
typedef __attribute__((ext_vector_type(8))) short short8;

// f32 -> bf16 (round-to-nearest-even), raw-bit version (finite inputs only)
__device__ __forceinline__ unsigned int f2bf(float x) {
  unsigned int u = __builtin_bit_cast(unsigned int, x);
  unsigned int rb = ((u >> 16) & 1u) + 0x7fffu;
  return (u + rb) >> 16;
}
__device__ __forceinline__ unsigned int f2bf2(float lo, float hi) {
  return f2bf(lo) | (f2bf(hi) << 16);
}

// async global->LDS, 16B per lane; LDS dest is wave-uniform base + lane*16
__device__ __forceinline__ void gld16(void* lds, const void* g) {
  __builtin_amdgcn_global_load_lds(
      (const __attribute__((address_space(1))) void*)g,
      (__attribute__((address_space(3))) void*)lds, 16, 0, 0);
}

// Single cooperative kernel: prep -> grid.sync -> triangular pair -> grid.sync -> final.
// Grid dim3(136,4) = 544 blocks; LDS 36.3KB -> 4 blocks/CU co-resident (>=544 total). 
__global__ __launch_bounds__(256, 4) void k_all(
    const float* __restrict__ f, const float* __restrict__ p,
    unsigned int* __restrict__ fnb, unsigned int* __restrict__ Eb,
    unsigned int* __restrict__ Pb, float* __restrict__ rowdot,
    float* __restrict__ partials, float* __restrict__ out) {
  __shared__ unsigned short As[64 * 64];
  __shared__ unsigned short Bs[64 * 64];
  __shared__ unsigned short Ese[64 * 40];  // ea for s rows (padded rows)
  __shared__ unsigned short Esp[64 * 40];  // p  for s rows
  __shared__ unsigned short Ele[64 * 40];  // ea for l rows
  __shared__ unsigned short Elp[64 * 40];  // p  for l rows
  __shared__ float4 red[4];

  cg::grid_group grid = cg::this_grid();
  const int tid = threadIdx.x;
  const int lane = tid & 63;
  const int wave = tid >> 6;
  const int lan = lane & 15, quad = lane >> 4;
  const int bid = blockIdx.y * 136 + blockIdx.x;

  // ---------- phase 1: prep ----------
  if (bid < 512) {
    // 8 f-rows per block, 2 per wave: sum squares, scale, pack bf16
#pragma unroll
    for (int rr = 0; rr < 2; ++rr) {
      int row = bid * 8 + wave * 2 + rr;
      const float* fr = f + (size_t)row * C;
      float2 v[3];
      float ss = 0.f;
#pragma unroll
      for (int j = 0; j < 3; ++j) {
        v[j] = *(const float2*)(fr + 2 * lane + 128 * j);
        ss = fmaf(v[j].x, v[j].x, fmaf(v[j].y, v[j].y, ss));
      }
#pragma unroll
      for (int m = 32; m >= 1; m >>= 1) ss += __shfl_xor(ss, m, 64);
      float s = 1.f / fmaxf(sqrtf(ss), 1e-12f);
      unsigned int* outr = fnb + (size_t)row * (C / 2);
#pragma unroll
      for (int j = 0; j < 3; ++j) outr[lane + 64 * j] = f2bf2(v[j].x * s, v[j].y * s);
    }
  } else {
    // 32 blocks for p-prep: each thread 2 quarter-row tasks
#pragma unroll
    for (int it = 0; it < 2; ++it) {
      int t = (bid - 512) * 512 + it * 256 + tid;  // [0, 16384)
      int r = t >> 2, q = t & 3;
      const float* pr = p + (size_t)r * NC + q * 8;
      float4 a = *(const float4*)pr;
      float4 b = *(const float4*)(pr + 4);
      float ea0 = __expf(a.x), ea1 = __expf(a.y), ea2 = __expf(a.z), ea3 = __expf(a.w);
      float eb0 = __expf(b.x), eb1 = __expf(b.y), eb2 = __expf(b.z), eb3 = __expf(b.w);
      uint4 ue = make_uint4(f2bf2(ea0, ea1), f2bf2(ea2, ea3), f2bf2(eb0, eb1), f2bf2(eb2, eb3));
      uint4 up = make_uint4(f2bf2(a.x, a.y), f2bf2(a.z, a.w), f2bf2(b.x, b.y), f2bf2(b.z, b.w));
      *(uint4*)(Eb + r * 16 + q * 4) = ue;
      *(uint4*)(Pb + r * 16 + q * 4) = up;
      float s = ea0 * a.x + ea1 * a.y + ea2 * a.z + ea3 * a.w +
                eb0 * b.x + eb1 * b.y + eb2 * b.z + eb3 * b.w;
      s += __shfl_xor(s, 1, 64);
      s += __shfl_xor(s, 2, 64);
      if (q == 0) rowdot[r] = s;
    }
  }
  __threadfence();
  grid.sync();

  // ---------- phase 2: triangular pairwise (R7 core) ----------
  // f_corr symmetric -> each unordered pair once: s<l weight 2-way, diag once.
  const unsigned short* fnb_r = (const unsigned short*)fnb;
  const unsigned short* Eb_r = (const unsigned short*)Eb;
  const unsigned short* Pb_r = (const unsigned short*)Pb;
  const int n = blockIdx.y;

  int rem = blockIdx.x, ty = 0;
  while (rem >= 16 - ty) {
    rem -= 16 - ty;
    ++ty;
  }
  const int tx = ty + rem;
  const int sBase = ty * 64;
  const int lBase = tx * 64;

  const int r8 = lane >> 3, c8 = lane & 7;
  const char* gA = (const char*)fnb_r +
                   ((size_t)(n * S + sBase + 16 * wave + r8)) * 768 + ((c8 ^ r8) << 4);
  const char* gB = (const char*)fnb_r +
                   ((size_t)(n * S + lBase + 16 * wave + r8)) * 768 + ((c8 ^ r8) << 4);
  char* lA = (char*)As + (16 * wave) * 128;
  char* lB = (char*)Bs + (16 * wave) * 128;

  {
    int row = tid >> 2, q = tid & 3;
    *(uint4*)(&Ese[row * 40 + q * 8]) =
        *(const uint4*)(Eb_r + (size_t)(n * S + sBase + row) * 32 + q * 8);
    *(uint4*)(&Esp[row * 40 + q * 8]) =
        *(const uint4*)(Pb_r + (size_t)(n * S + sBase + row) * 32 + q * 8);
    *(uint4*)(&Ele[row * 40 + q * 8]) =
        *(const uint4*)(Eb_r + (size_t)(n * S + lBase + row) * 32 + q * 8);
    *(uint4*)(&Elp[row * 40 + q * 8]) =
        *(const uint4*)(Pb_r + (size_t)(n * S + lBase + row) * 32 + q * 8);
  }

  f32x4 acc[4];
#pragma unroll
  for (int j = 0; j < 4; ++j) acc[j] = (f32x4){0.f, 0.f, 0.f, 0.f};

  for (int kt = 0; kt < 6; ++kt) {
    gld16(lA, gA + kt * 128);
    gld16(lA + 8 * 128, gA + 8 * 768 + kt * 128);
    gld16(lB, gB + kt * 128);
    gld16(lB + 8 * 128, gB + 8 * 768 + kt * 128);
    __syncthreads();
#pragma unroll
    for (int ks = 0; ks < 2; ++ks) {
      short8 af, bfr[4];
      {
        int rowA = 16 * wave + lan;
        af = *(const short8*)((const char*)As + rowA * 128 +
                              ((((ks << 2) | quad) ^ (lan & 7)) << 4));
      }
#pragma unroll
      for (int t = 0; t < 4; ++t) {
        int rowB = t * 16 + lan;
        bfr[t] = *(const short8*)((const char*)Bs + rowB * 128 +
                                  ((((ks << 2) | quad) ^ (lan & 7)) << 4));
      }
#pragma unroll
      for (int j = 0; j < 4; ++j)
        acc[j] = __builtin_amdgcn_mfma_f32_16x16x32_bf16(af, bfr[j], acc[j], 0, 0, 0);
    }
    __syncthreads();
  }

  // epilogue: dual EP mini-GEMMs + weighted triangular reduction
  // C/D layout: row(m=s) = quad*4+reg, col(n=l) = lan
  short8 eas, ps;
  {
    int row = 16 * wave + lan;
    eas = *(const short8*)(&Ese[row * 40 + quad * 8]);
    ps = *(const short8*)(&Esp[row * 40 + quad * 8]);
  }
  float rd_s[4];
  {
    int gs0 = n * S + sBase + 16 * wave + quad * 4;
#pragma unroll
    for (int r = 0; r < 4; ++r) rd_s[r] = rowdot[gs0 + r];
  }

  float pos_s = 0.f, neg_s = 0.f, posc = 0.f, negc = 0.f;
#pragma unroll
  for (int j = 0; j < 4; ++j) {
    short8 pl = *(const short8*)(&Elp[(j * 16 + lan) * 40 + quad * 8]);
    short8 eal = *(const short8*)(&Ele[(j * 16 + lan) * 40 + quad * 8]);
    f32x4 z = (f32x4){0.f, 0.f, 0.f, 0.f};
    f32x4 ep1 = __builtin_amdgcn_mfma_f32_16x16x32_bf16(eas, pl, z, 0, 0, 0);
    f32x4 ep2 = __builtin_amdgcn_mfma_f32_16x16x32_bf16(ps, eal, z, 0, 0, 0);
    int gl = lBase + j * 16 + lan;
    float rd_l = rowdot[n * S + gl];
#pragma unroll
    for (int r = 0; r < 4; ++r) {
      int gs = sBase + 16 * wave + quad * 4 + r;
      float w1 = (gl >= gs) ? 1.f : 0.f;
      float w2 = (gl > gs) ? 1.f : 0.f;
      float fc = acc[j][r] - SHIFT;
      float contrib = w1 * (rd_s[r] - ep1[r]) + w2 * (rd_l - ep2[r]);
      float cnt = w1 + w2;
      if (fc > 0.f) {
        pos_s = fmaf(fc, contrib, pos_s);
        posc += cnt;
      } else if (fc < 0.f) {
        neg_s = fmaf(fc, contrib, neg_s);
        negc += cnt;
      }
    }
  }
#pragma unroll
  for (int m = 32; m >= 1; m >>= 1) {
    pos_s += __shfl_xor(pos_s, m, 64);
    neg_s += __shfl_xor(neg_s, m, 64);
    posc += __shfl_xor(posc, m, 64);
    negc += __shfl_xor(negc, m, 64);
  }
  if (lane == 0) {
    *(float4*)(&partials[(bid * 4 + wave) * 4]) = make_float4(pos_s, neg_s, posc, negc);
  }
  __threadfence();
  grid.sync();

  // ---------- phase 3: block 0 reduces 2176 float4 partials ----------
  if (bid == 0) {
    float4 s = make_float4(0.f, 0.f, 0.f, 0.f);
#pragma unroll
    for (int i = 0; i < 9; ++i) {
      int idx = tid + i * 256;
      if (idx < 2176) {
        float4 v = ((const float4*)partials)[idx];
        s.x += v.x;
        s.y += v.y;
        s.z += v.z;
        s.w += v.w;
      }
    }
#pragma unroll
    for (int m = 32; m >= 1; m >>= 1) {
      s.x += __shfl_xor(s.x, m, 64);
      s.y += __shfl_xor(s.y, m, 64);
      s.z += __shfl_xor(s.z, m, 64);
      s.w += __shfl_xor(s.w, m, 64);
    }
    if ((tid & 63) == 0) red[tid >> 6] = s;
    __syncthreads();
    if (tid == 0) {
      float4 t = red[0];
#pragma unroll
      for (int w = 1; w < 4; ++w) {
        t.x += red[w].x;
        t.y += red[w].y;
        t.z += red[w].z;
        t.w += red[w].w;
      }
      out[0] = t.x / t.z;
      out[1] = t.y / t.w;
    }
  }
}

extern "C" void kernel_launch(void* const* d_in, const int* in_sizes, int n_in,
                              void* d_out, int out_size, void* d_ws, size_t ws_size,
                              hipStream_t stream) {
  const float* f = (const float*)d_in[0];  // feats [4,32,32,384] f32
  const float* p = (const float*)d_in[1];  // p_class [4,32,32,32] f32 (log-probs)
  float* out = (float*)d_out;              // [pos, neg]
  float* ws = (float*)d_ws;
  // ws layout (floats): rowdot @0 (4096) | partials @4096 (2176*4=8704, pad) |
  // fnb @16384 (786432) | Eb @802816 (65536) | Pb @868352 (65536)
  float* rowdot = ws;
  float* partials = ws + 4096;
  unsigned int* fnb = (unsigned int*)(ws + 16384);
  unsigned int* Eb = (unsigned int*)(ws + 802816);
  unsigned int* Pb = (unsigned int*)(ws + 868352);

  void* args[] = {(void*)&f, (void*)&p, (void*)&fnb, (void*)&Eb,
                  (void*)&Pb, (void*)&rowdot, (void*)&partials, (void*)&out};
  hipLaunchCooperativeKernel((const void*)k_all, dim3(136, 4), dim3(256), args, 0, stream);
}

// Round 9
// 103.918 us; speedup vs baseline: 2.5230x; 2.5230x over previous
//
#include <hip/hip_runtime.h>
#include <hip/hip_bf16.h>

#define S 1024
#define C 384
#define NC 32
#define SHIFT 0.3f
#define MAGIC 0x5EEDF00Du

typedef __attribute__((ext_vector_type(4))) float f32x4;
typedef __attribute__((ext_vector_type(8))) short short8;

// f32 -> bf16 (round-to-nearest-even), raw-bit version (finite inputs only)
__device__ __forceinline__ unsigned int f2bf(float x) {
  unsigned int u = __builtin_bit_cast(unsigned int, x);
  unsigned int rb = ((u >> 16) & 1u) + 0x7fffu;
  return (u + rb) >> 16;
}
__device__ __forceinline__ unsigned int f2bf2(float lo, float hi) {
  return f2bf(lo) | (f2bf(hi) << 16);
}
__device__ __forceinline__ unsigned long long pack2f(float a, float b) {
  return (unsigned long long)__builtin_bit_cast(unsigned int, a) |
         ((unsigned long long)__builtin_bit_cast(unsigned int, b) << 32);
}

// ONE plain launch. Each block self-prepares its 128 rows (invnorm, exp(p), p,
// rowdot) from f/p directly (no global intermediates, no grid sync), runs the
// R7 triangular 64x64 MFMA core, publishes partials via device-scope atomics,
// and block 0 (lone spinner on per-block flags) reduces + writes out.
__global__ __launch_bounds__(256, 4) void k_fused(
    const float* __restrict__ f, const float* __restrict__ p,
    unsigned int* __restrict__ flags, unsigned long long* __restrict__ partials,
    float* __restrict__ out) {
  __shared__ unsigned short As[64 * 72];  // padded rows: R3-proven conflict-free
  __shared__ unsigned short Bs[64 * 72];
  __shared__ unsigned short Ese[64 * 40];  // ea for s rows
  __shared__ unsigned short Esp[64 * 40];  // p  for s rows
  __shared__ unsigned short Ele[64 * 40];  // ea for l rows
  __shared__ unsigned short Elp[64 * 40];  // p  for l rows
  __shared__ float invnL[128];             // [0,64): s rows, [64,128): l rows
  __shared__ float rdL[128];
  __shared__ float4 red[4];

  const int tid = threadIdx.x;
  const int lane = tid & 63;
  const int wave = tid >> 6;
  const int lan = lane & 15, quad = lane >> 4;
  const int n = blockIdx.y;
  const int bid = blockIdx.y * 136 + blockIdx.x;

  // triangular tile decode: bx -> (ty, tx), tx >= ty
  int rem = blockIdx.x, ty = 0;
  while (rem >= 16 - ty) {
    rem -= 16 - ty;
    ++ty;
  }
  const int tx = ty + rem;
  const int sBase = ty * 64, lBase = tx * 64;

  // ---- in-block prep: 2 threads per row (128 rows = 64 s + 64 l) ----
  const int row128 = tid >> 1, half = tid & 1;
  const int growA = n * S + ((row128 < 64) ? (sBase + row128) : (lBase + row128 - 64));
  {
    // invnorm: each thread sums 192 of the row's 384 squares
    const float* fr = f + (size_t)growA * C + half * 192;
    float ss = 0.f;
    for (int j = 0; j < 48; ++j) {
      float4 v = *(const float4*)(fr + j * 4);
      ss = fmaf(v.x, v.x, fmaf(v.y, v.y, fmaf(v.z, v.z, fmaf(v.w, v.w, ss))));
    }
    ss += __shfl_xor(ss, 1, 64);
    if (half == 0) invnL[row128] = 1.f / fmaxf(sqrtf(ss), 1e-12f);
  }
  {
    // E/P pack + rowdot: each thread handles 16 of the row's 32 classes
    const float* pr = p + (size_t)growA * NC + half * 16;
    float4 a = *(const float4*)pr;
    float4 b = *(const float4*)(pr + 4);
    float4 c = *(const float4*)(pr + 8);
    float4 d = *(const float4*)(pr + 12);
    float e0 = __expf(a.x), e1 = __expf(a.y), e2 = __expf(a.z), e3 = __expf(a.w);
    float e4 = __expf(b.x), e5 = __expf(b.y), e6 = __expf(b.z), e7 = __expf(b.w);
    float e8 = __expf(c.x), e9 = __expf(c.y), e10 = __expf(c.z), e11 = __expf(c.w);
    float e12 = __expf(d.x), e13 = __expf(d.y), e14 = __expf(d.z), e15 = __expf(d.w);
    uint4 elo = make_uint4(f2bf2(e0, e1), f2bf2(e2, e3), f2bf2(e4, e5), f2bf2(e6, e7));
    uint4 ehi = make_uint4(f2bf2(e8, e9), f2bf2(e10, e11), f2bf2(e12, e13), f2bf2(e14, e15));
    uint4 plo = make_uint4(f2bf2(a.x, a.y), f2bf2(a.z, a.w), f2bf2(b.x, b.y), f2bf2(b.z, b.w));
    uint4 phi = make_uint4(f2bf2(c.x, c.y), f2bf2(c.z, c.w), f2bf2(d.x, d.y), f2bf2(d.z, d.w));
    unsigned short* de = (row128 < 64) ? &Ese[row128 * 40] : &Ele[(row128 - 64) * 40];
    unsigned short* dp = (row128 < 64) ? &Esp[row128 * 40] : &Elp[(row128 - 64) * 40];
    *(uint4*)(de + half * 16) = elo;
    *(uint4*)(de + half * 16 + 8) = ehi;
    *(uint4*)(dp + half * 16) = plo;
    *(uint4*)(dp + half * 16 + 8) = phi;
    float rd = e0 * a.x + e1 * a.y + e2 * a.z + e3 * a.w + e4 * b.x + e5 * b.y +
               e6 * b.z + e7 * b.w + e8 * c.x + e9 * c.y + e10 * c.z + e11 * c.w +
               e12 * d.x + e13 * d.y + e14 * d.z + e15 * d.w;
    rd += __shfl_xor(rd, 1, 64);
    if (half == 0) rdL[row128] = rd;
  }
  __syncthreads();

  // ---- main K loop: 6 chunks of BK=64; VALU stage (scale+convert) from L2-warm f ----
  const int srow = tid >> 2, sq = tid & 3;  // 4 threads per row, 16 cols each
  const float* srcA0 = f + (size_t)(n * S + sBase + srow) * C + sq * 16;
  const float* srcB0 = f + (size_t)(n * S + lBase + srow) * C + sq * 16;

  f32x4 acc[4];
#pragma unroll
  for (int j = 0; j < 4; ++j) acc[j] = (f32x4){0.f, 0.f, 0.f, 0.f};

  for (int kt = 0; kt < 6; ++kt) {
    {
      float sa = invnL[srow];
      const float* sA = srcA0 + kt * 64;
      float4 x0 = *(const float4*)(sA);
      float4 x1 = *(const float4*)(sA + 4);
      float4 x2 = *(const float4*)(sA + 8);
      float4 x3 = *(const float4*)(sA + 12);
      uint4 lo = make_uint4(f2bf2(x0.x * sa, x0.y * sa), f2bf2(x0.z * sa, x0.w * sa),
                            f2bf2(x1.x * sa, x1.y * sa), f2bf2(x1.z * sa, x1.w * sa));
      uint4 hi = make_uint4(f2bf2(x2.x * sa, x2.y * sa), f2bf2(x2.z * sa, x2.w * sa),
                            f2bf2(x3.x * sa, x3.y * sa), f2bf2(x3.z * sa, x3.w * sa));
      *(uint4*)(&As[srow * 72 + sq * 16]) = lo;
      *(uint4*)(&As[srow * 72 + sq * 16 + 8]) = hi;
      float sb = invnL[64 + srow];
      const float* sB = srcB0 + kt * 64;
      float4 y0 = *(const float4*)(sB);
      float4 y1 = *(const float4*)(sB + 4);
      float4 y2 = *(const float4*)(sB + 8);
      float4 y3 = *(const float4*)(sB + 12);
      uint4 lo2 = make_uint4(f2bf2(y0.x * sb, y0.y * sb), f2bf2(y0.z * sb, y0.w * sb),
                             f2bf2(y1.x * sb, y1.y * sb), f2bf2(y1.z * sb, y1.w * sb));
      uint4 hi2 = make_uint4(f2bf2(y2.x * sb, y2.y * sb), f2bf2(y2.z * sb, y2.w * sb),
                             f2bf2(y3.x * sb, y3.y * sb), f2bf2(y3.z * sb, y3.w * sb));
      *(uint4*)(&Bs[srow * 72 + sq * 16]) = lo2;
      *(uint4*)(&Bs[srow * 72 + sq * 16 + 8]) = hi2;
    }
    __syncthreads();
#pragma unroll
    for (int ks = 0; ks < 2; ++ks) {
      short8 af, bfr[4];
      af = *(const short8*)(&As[(16 * wave + lan) * 72 + ks * 32 + quad * 8]);
#pragma unroll
      for (int t = 0; t < 4; ++t)
        bfr[t] = *(const short8*)(&Bs[(t * 16 + lan) * 72 + ks * 32 + quad * 8]);
#pragma unroll
      for (int j = 0; j < 4; ++j)
        acc[j] = __builtin_amdgcn_mfma_f32_16x16x32_bf16(af, bfr[j], acc[j], 0, 0, 0);
    }
    __syncthreads();
  }

  // ---- epilogue: dual EP mini-GEMMs + weighted triangular reduction ----
  // C/D layout: row(m=s) = quad*4+reg, col(n=l) = lan
  short8 eas, ps;
  {
    int row = 16 * wave + lan;
    eas = *(const short8*)(&Ese[row * 40 + quad * 8]);
    ps = *(const short8*)(&Esp[row * 40 + quad * 8]);
  }
  float rd_s[4];
#pragma unroll
  for (int r = 0; r < 4; ++r) rd_s[r] = rdL[16 * wave + quad * 4 + r];

  float pos_s = 0.f, neg_s = 0.f, posc = 0.f, negc = 0.f;
#pragma unroll
  for (int j = 0; j < 4; ++j) {
    short8 pl = *(const short8*)(&Elp[(j * 16 + lan) * 40 + quad * 8]);
    short8 eal = *(const short8*)(&Ele[(j * 16 + lan) * 40 + quad * 8]);
    f32x4 z = (f32x4){0.f, 0.f, 0.f, 0.f};
    f32x4 ep1 = __builtin_amdgcn_mfma_f32_16x16x32_bf16(eas, pl, z, 0, 0, 0);
    f32x4 ep2 = __builtin_amdgcn_mfma_f32_16x16x32_bf16(ps, eal, z, 0, 0, 0);
    int gl = lBase + j * 16 + lan;
    float rd_l = rdL[64 + j * 16 + lan];
#pragma unroll
    for (int r = 0; r < 4; ++r) {
      int gs = sBase + 16 * wave + quad * 4 + r;
      float w1 = (gl >= gs) ? 1.f : 0.f;
      float w2 = (gl > gs) ? 1.f : 0.f;
      float fc = acc[j][r] - SHIFT;
      float contrib = w1 * (rd_s[r] - ep1[r]) + w2 * (rd_l - ep2[r]);
      float cnt = w1 + w2;
      if (fc > 0.f) {
        pos_s = fmaf(fc, contrib, pos_s);
        posc += cnt;
      } else if (fc < 0.f) {
        neg_s = fmaf(fc, contrib, neg_s);
        negc += cnt;
      }
    }
  }
#pragma unroll
  for (int m = 32; m >= 1; m >>= 1) {
    pos_s += __shfl_xor(pos_s, m, 64);
    neg_s += __shfl_xor(neg_s, m, 64);
    posc += __shfl_xor(posc, m, 64);
    negc += __shfl_xor(negc, m, 64);
  }
  // publish partials via device-scope atomics (coherent across XCDs)
  if (lane == 0) {
    atomicExch(&partials[(bid * 4 + wave) * 2], pack2f(pos_s, neg_s));
    atomicExch(&partials[(bid * 4 + wave) * 2 + 1], pack2f(posc, negc));
  }
  __syncthreads();  // all waves' atomics issued & drained (barrier waits vmcnt)
  if (tid == 0) {
    __threadfence();
    atomicExch(&flags[bid], MAGIC);
  }

  // ---- block 0: lone spinner, then final reduction ----
  if (bid == 0) {
    bool ok;
    do {
      ok = true;
      for (int idx = tid; idx < 544; idx += 256)
        ok &= (atomicOr(&flags[idx], 0u) == MAGIC);
      if (!ok) __builtin_amdgcn_s_sleep(8);
    } while (!__syncthreads_and(ok));

    float4 s = make_float4(0.f, 0.f, 0.f, 0.f);
    for (int idx = tid; idx < 2176; idx += 256) {
      unsigned long long u1 = atomicOr(&partials[idx * 2], 0ull);
      unsigned long long u2 = atomicOr(&partials[idx * 2 + 1], 0ull);
      s.x += __builtin_bit_cast(float, (unsigned int)(u1 & 0xffffffffu));
      s.y += __builtin_bit_cast(float, (unsigned int)(u1 >> 32));
      s.z += __builtin_bit_cast(float, (unsigned int)(u2 & 0xffffffffu));
      s.w += __builtin_bit_cast(float, (unsigned int)(u2 >> 32));
    }
#pragma unroll
    for (int m = 32; m >= 1; m >>= 1) {
      s.x += __shfl_xor(s.x, m, 64);
      s.y += __shfl_xor(s.y, m, 64);
      s.z += __shfl_xor(s.z, m, 64);
      s.w += __shfl_xor(s.w, m, 64);
    }
    if ((tid & 63) == 0) red[tid >> 6] = s;
    __syncthreads();
    if (tid == 0) {
      float4 t = red[0];
#pragma unroll
      for (int w = 1; w < 4; ++w) {
        t.x += red[w].x;
        t.y += red[w].y;
        t.z += red[w].z;
        t.w += red[w].w;
      }
      out[0] = t.x / t.z;
      out[1] = t.y / t.w;
    }
  }
}

extern "C" void kernel_launch(void* const* d_in, const int* in_sizes, int n_in,
                              void* d_out, int out_size, void* d_ws, size_t ws_size,
                              hipStream_t stream) {
  const float* f = (const float*)d_in[0];  // feats [4,32,32,384] f32
  const float* p = (const float*)d_in[1];  // p_class [4,32,32,32] f32 (log-probs)
  float* out = (float*)d_out;              // [pos, neg]
  // ws layout (bytes): flags u32[1024] @0 | partials u64[4352] @4096
  unsigned int* flags = (unsigned int*)d_ws;
  unsigned long long* partials = (unsigned long long*)((char*)d_ws + 4096);

  k_fused<<<dim3(136, 4), dim3(256), 0, stream>>>(f, p, flags, partials, out);
}